// Round 1
// baseline (3834.504 us; speedup 1.0000x reference)
//
#include <hip/hip_runtime.h>
#include <hip/hip_bf16.h>
#include <stdint.h>

// ---------------------------------------------------------------------------
// OffsetHead: pointwise MLP (64->32->16->3) + revoxelize (unique rows + means)
//
// R3 changes vs R2:
//   * k_mlp: 2 rows/thread + 1-chunk-ahead software pipeline. Each broadcast
//     LDS weight read now feeds 8 FMAs (was 4) -> LDS-issue no longer exceeds
//     FMA-issue; two independent load streams per thread double bytes in
//     flight (k_mlp was latency-bound at 2.1 TB/s). Per-row fmaf order is
//     bitwise-identical to R2 (rint boundary behavior preserved).
//   * k_passA writes the sorted bucket back to slots; k_passB skips the
//     21-step bitonic re-sort (identical sorted input -> identical ranks).
// ---------------------------------------------------------------------------

#define TPB 256
#define NB 139264          // 2048 * 68
#define NCHUNK 544         // NB / 256
typedef unsigned long long ull;

__device__ __forceinline__ void epilogue(
    int i, float o0, float o1, float o2,
    const int* __restrict__ coords, const unsigned char* __restrict__ mask,
    float* __restrict__ out_off, ull* __restrict__ slots,
    unsigned int* __restrict__ cursor)
{
    float m = mask[i] ? 1.0f : 0.0f;
    o0 *= m; o1 *= m; o2 *= m;
    out_off[(size_t)3 * i + 0] = o0;
    out_off[(size_t)3 * i + 1] = o1;
    out_off[(size_t)3 * i + 2] = o2;

    // Key build: round-half-even (rintf == v_rndne, matches jnp.round)
    int4 c = ((const int4*)coords)[i];
    int r1 = (int)rintf(o0), r2 = (int)rintf(o1), r3 = (int)rintf(o2);
    int c1u = c.y + r1, c2u = c.z + r2, c3u = c.w + r3;
    int c1s = min(max(c1u + 1024, 0), 8191);
    int c2s = min(max(c2u + 1024, 0), 8191);
    int c3s = min(max(c3u + 1024, 0), 8191);
    int bin1 = min(max((c1u + 64) >> 5, 0), 67);
    int b = c.x * 68 + bin1;
    ull row39 = ((ull)c1s << 26) | ((ull)c2s << 13) | (ull)c3s;
    ull packed = (row39 << 20) | (ull)(unsigned int)i;
    unsigned int j = atomicAdd(&cursor[b], 1u);
    if (j < 64u) slots[(size_t)b * 64 + j] = packed;
}

__global__ __launch_bounds__(256) void k_mlp(
    const float* __restrict__ feats, const int* __restrict__ coords,
    const unsigned char* __restrict__ mask,
    const float* __restrict__ W1, const float* __restrict__ b1,
    const float* __restrict__ W2, const float* __restrict__ b2,
    const float* __restrict__ W3, const float* __restrict__ b3,
    float* __restrict__ out_off, ull* __restrict__ slots,
    unsigned int* __restrict__ cursor, int n)
{
    __shared__ float sW1[2048];
    __shared__ float sW2[512];
    __shared__ float sW3[48];
    __shared__ float sb1[32];
    __shared__ float sb2[16];
    __shared__ float sb3[3];
    for (int t = threadIdx.x; t < 2048; t += TPB) sW1[t] = W1[t];
    for (int t = threadIdx.x; t < 512;  t += TPB) sW2[t] = W2[t];
    if (threadIdx.x < 48) sW3[threadIdx.x] = W3[threadIdx.x];
    if (threadIdx.x < 32) sb1[threadIdx.x] = b1[threadIdx.x];
    if (threadIdx.x < 16) sb2[threadIdx.x] = b2[threadIdx.x];
    if (threadIdx.x < 3)  sb3[threadIdx.x] = b3[threadIdx.x];
    __syncthreads();

    int i0 = blockIdx.x * (2 * TPB) + threadIdx.x;
    int i1 = i0 + TPB;
    if (i0 >= n) return;
    bool v1 = (i1 < n);

    const float4* fa = (const float4*)(feats + (size_t)i0 * 64);
    const float4* fb = (const float4*)(feats + (size_t)(v1 ? i1 : i0) * 64);

    // Layer 1: ascending-k FMA accumulation, bias added AFTER (match XLA GEMM).
    // Two rows interleaved; per-row op order identical to R2.
    float h1a[32], h1b[32];
    #pragma unroll
    for (int j = 0; j < 32; ++j) { h1a[j] = 0.0f; h1b[j] = 0.0f; }

    float4 ac = fa[0];
    float4 bc = fb[0];
    #pragma unroll
    for (int kc = 0; kc < 16; ++kc) {
        float4 an, bn;
        if (kc < 15) { an = fa[kc + 1]; bn = fb[kc + 1]; }
        #pragma unroll
        for (int d = 0; d < 4; ++d) {
            float xa = (d == 0) ? ac.x : (d == 1) ? ac.y : (d == 2) ? ac.z : ac.w;
            float xb = (d == 0) ? bc.x : (d == 1) ? bc.y : (d == 2) ? bc.z : bc.w;
            const float* wr = &sW1[(kc * 4 + d) * 32];
            #pragma unroll
            for (int j = 0; j < 32; j += 4) {
                float4 w = *(const float4*)(wr + j);
                h1a[j + 0] = fmaf(xa, w.x, h1a[j + 0]);
                h1a[j + 1] = fmaf(xa, w.y, h1a[j + 1]);
                h1a[j + 2] = fmaf(xa, w.z, h1a[j + 2]);
                h1a[j + 3] = fmaf(xa, w.w, h1a[j + 3]);
                h1b[j + 0] = fmaf(xb, w.x, h1b[j + 0]);
                h1b[j + 1] = fmaf(xb, w.y, h1b[j + 1]);
                h1b[j + 2] = fmaf(xb, w.z, h1b[j + 2]);
                h1b[j + 3] = fmaf(xb, w.w, h1b[j + 3]);
            }
        }
        ac = an; bc = bn;
    }
    #pragma unroll
    for (int j = 0; j < 32; ++j) {
        h1a[j] = fmaxf(h1a[j] + sb1[j], 0.0f);
        h1b[j] = fmaxf(h1b[j] + sb1[j], 0.0f);
    }

    // Layer 2
    float h2a[16], h2b[16];
    #pragma unroll
    for (int j = 0; j < 16; ++j) { h2a[j] = 0.0f; h2b[j] = 0.0f; }
    #pragma unroll
    for (int k = 0; k < 32; ++k) {
        float xa = h1a[k], xb = h1b[k];
        const float* wr = &sW2[k * 16];
        #pragma unroll
        for (int j = 0; j < 16; j += 4) {
            float4 w = *(const float4*)(wr + j);
            h2a[j + 0] = fmaf(xa, w.x, h2a[j + 0]);
            h2a[j + 1] = fmaf(xa, w.y, h2a[j + 1]);
            h2a[j + 2] = fmaf(xa, w.z, h2a[j + 2]);
            h2a[j + 3] = fmaf(xa, w.w, h2a[j + 3]);
            h2b[j + 0] = fmaf(xb, w.x, h2b[j + 0]);
            h2b[j + 1] = fmaf(xb, w.y, h2b[j + 1]);
            h2b[j + 2] = fmaf(xb, w.z, h2b[j + 2]);
            h2b[j + 3] = fmaf(xb, w.w, h2b[j + 3]);
        }
    }
    #pragma unroll
    for (int j = 0; j < 16; ++j) {
        h2a[j] = fmaxf(h2a[j] + sb2[j], 0.0f);
        h2b[j] = fmaxf(h2b[j] + sb2[j], 0.0f);
    }

    // Layer 3
    float o0a = 0.0f, o1a = 0.0f, o2a = 0.0f;
    float o0b = 0.0f, o1b = 0.0f, o2b = 0.0f;
    #pragma unroll
    for (int k = 0; k < 16; ++k) {
        float xa = h2a[k], xb = h2b[k];
        float w0 = sW3[k * 3 + 0], w1 = sW3[k * 3 + 1], w2 = sW3[k * 3 + 2];
        o0a = fmaf(xa, w0, o0a);
        o1a = fmaf(xa, w1, o1a);
        o2a = fmaf(xa, w2, o2a);
        o0b = fmaf(xb, w0, o0b);
        o1b = fmaf(xb, w1, o1b);
        o2b = fmaf(xb, w2, o2b);
    }
    o0a += sb3[0]; o1a += sb3[1]; o2a += sb3[2];
    o0b += sb3[0]; o1b += sb3[1]; o2b += sb3[2];

    epilogue(i0, o0a, o1a, o2a, coords, mask, out_off, slots, cursor);
    if (v1)
        epilogue(i1, o0b, o1b, o2b, coords, mask, out_off, slots, cursor);
}

// Wave-register bitonic sort of up to 64 packed u64s (padding = ~0ULL).
__device__ inline ull wave_sort64(ull v, int lane)
{
    #pragma unroll
    for (int k = 2; k <= 64; k <<= 1) {
        #pragma unroll
        for (int j = k >> 1; j > 0; j >>= 1) {
            ull o = __shfl_xor(v, j, 64);
            bool up = ((lane & k) == 0);
            bool lower = ((lane & j) == 0);
            ull mn = (v < o) ? v : o;
            ull mx = (v < o) ? o : v;
            v = (up == lower) ? mn : mx;
        }
    }
    return v;
}

// Pass A: sort each bucket, write sorted bucket back, count unique rows.
__global__ __launch_bounds__(256) void k_passA(
    ull* __restrict__ slots, const unsigned int* __restrict__ cursor,
    unsigned int* __restrict__ ucnt)
{
    int lane = threadIdx.x & 63;
    int b = blockIdx.x * 4 + (threadIdx.x >> 6);
    unsigned int cnt = cursor[b];
    if (cnt > 64u) cnt = 64u;
    if (cnt == 0u) { if (lane == 0) ucnt[b] = 0u; return; }
    ull v = (lane < (int)cnt) ? slots[(size_t)b * 64 + lane] : ~0ULL;
    v = wave_sort64(v, lane);
    if (lane < (int)cnt) slots[(size_t)b * 64 + lane] = v;  // persist sorted
    ull row = v >> 20;
    ull prev = __shfl_up(row, 1, 64);
    bool head = (lane < (int)cnt) && ((lane == 0) || (row != prev));
    ull hm = __ballot(head);
    if (lane == 0) ucnt[b] = (unsigned int)__popcll(hm);
}

// Scan level 1: exclusive scan within 256-entry chunks.
__global__ __launch_bounds__(256) void k_scanA(
    const unsigned int* __restrict__ ucnt, unsigned int* __restrict__ lstart,
    unsigned int* __restrict__ chsum)
{
    __shared__ unsigned int s[256];
    int tid = threadIdx.x;
    int g = blockIdx.x * 256 + tid;
    unsigned int v = ucnt[g];
    s[tid] = v;
    __syncthreads();
    for (int ofs = 1; ofs < 256; ofs <<= 1) {
        unsigned int t = (tid >= ofs) ? s[tid - ofs] : 0u;
        __syncthreads();
        s[tid] += t;
        __syncthreads();
    }
    lstart[g] = s[tid] - v;
    if (tid == 255) chsum[blockIdx.x] = s[255];
}

// Scan level 2: exclusive scan of chunk sums (in place).
__global__ __launch_bounds__(1024) void k_scanB(unsigned int* __restrict__ chsum)
{
    __shared__ unsigned int s[1024];
    int tid = threadIdx.x;
    unsigned int v = (tid < NCHUNK) ? chsum[tid] : 0u;
    s[tid] = v;
    __syncthreads();
    for (int ofs = 1; ofs < 1024; ofs <<= 1) {
        unsigned int t = (tid >= ofs) ? s[tid - ofs] : 0u;
        __syncthreads();
        s[tid] += t;
        __syncthreads();
    }
    if (tid < NCHUNK) chsum[tid] = s[tid] - v;
}

// Pass B: read pre-sorted buckets, compute global ranks, write inv + means.
__global__ __launch_bounds__(256) void k_passB(
    const ull* __restrict__ slots, const unsigned int* __restrict__ cursor,
    const unsigned int* __restrict__ lstart, const unsigned int* __restrict__ chbase,
    float* __restrict__ out_oc, float* __restrict__ out_inv)
{
    int lane = threadIdx.x & 63;
    int b = blockIdx.x * 4 + (threadIdx.x >> 6);
    unsigned int cnt = cursor[b];
    if (cnt > 64u) cnt = 64u;
    if (cnt == 0u) return;
    // slots[b] was sorted in-place by k_passA; no re-sort needed.
    ull v = (lane < (int)cnt) ? slots[(size_t)b * 64 + lane] : ~0ULL;
    ull row = v >> 20;
    unsigned int idx = (unsigned int)(v & 0xFFFFFULL);
    ull prev = __shfl_up(row, 1, 64);
    bool head = (lane < (int)cnt) && ((lane == 0) || (row != prev));
    ull hm = __ballot(head);
    ull le = (lane == 63) ? ~0ULL : ((1ULL << (lane + 1)) - 1ULL);
    int lrank = __popcll(hm & le) - 1;          // 0-based within bucket
    unsigned int base = chbase[b >> 8] + lstart[b];
    unsigned int r = base + (unsigned int)lrank;
    if (lane < (int)cnt) out_inv[idx] = (float)r;

    // packed (count, c1sum, c2sum, c3sum): 7 + 19 + 19 + 19 bits
    int c3s = (int)(row & 0x1FFFULL);
    int c2s = (int)((row >> 13) & 0x1FFFULL);
    int c1s = (int)(row >> 26);
    ull sum = (lane < (int)cnt)
        ? ((1ULL << 57) | ((ull)c1s << 38) | ((ull)c2s << 19) | (ull)c3s)
        : 0ULL;
    ull P = sum;
    #pragma unroll
    for (int d = 1; d < 64; d <<= 1) {
        ull t = __shfl_up(P, d, 64);
        if (lane >= d) P += t;
    }
    ull gt = hm & ~le;                          // heads strictly above this lane
    int tpos = gt ? (__ffsll((long long)gt) - 2) : ((int)cnt - 1);
    ull Pt = __shfl(P, tpos, 64);
    int hsrc = (lane > 0) ? lane - 1 : 0;
    ull Ph = __shfl(P, hsrc, 64);
    if (lane == 0) Ph = 0ULL;
    if (head) {
        ull run = Pt - Ph;
        int rc = (int)(run >> 57);
        int s1 = (int)((run >> 38) & 0x7FFFFULL) - 1024 * rc;
        int s2 = (int)((run >> 19) & 0x7FFFFULL) - 1024 * rc;
        int s3 = (int)(run & 0x7FFFFULL) - 1024 * rc;
        float fc = (float)rc;
        float4 o;
        o.x = (float)((unsigned int)b / 68u);   // dim0 unchanged -> exact mean
        o.y = truncf((float)s1 / fc);
        o.z = truncf((float)s2 / fc);
        o.w = truncf((float)s3 / fc);
        ((float4*)out_oc)[r] = o;
    }
}

extern "C" void kernel_launch(void* const* d_in, const int* in_sizes, int n_in,
                              void* d_out, int out_size, void* d_ws, size_t ws_size,
                              hipStream_t stream)
{
    const float*         feats  = (const float*)d_in[0];
    const int*           coords = (const int*)d_in[1];
    const unsigned char* mask   = (const unsigned char*)d_in[2];
    const float* W1 = (const float*)d_in[3];
    const float* b1 = (const float*)d_in[4];
    const float* W2 = (const float*)d_in[5];
    const float* b2 = (const float*)d_in[6];
    const float* W3 = (const float*)d_in[7];
    const float* b3 = (const float*)d_in[8];

    int n = in_sizes[1] / 4;  // coords is [N,4]

    char* ws = (char*)d_ws;
    ull*          slots  = (ull*)ws;                                   // NB*64*8
    unsigned int* cursor = (unsigned int*)(ws + (size_t)NB * 64 * 8);  // NB*4 (zeroed)
    unsigned int* ucnt   = cursor + NB;                                // NB*4
    unsigned int* lstart = ucnt + NB;                                  // NB*4
    unsigned int* chsum  = lstart + NB;                                // NCHUNK*4

    float* out     = (float*)d_out;
    float* out_off = out;                  // [N,3] offsets (float32)
    float* out_oc  = out + (size_t)3 * n;  // [N,4] out_coords (as float values)
    float* out_inv = out + (size_t)7 * n;  // [N]   inv (as float values)

    hipMemsetAsync(cursor, 0, (size_t)NB * sizeof(unsigned int), stream);
    hipMemsetAsync(out_oc, 0, (size_t)4 * n * sizeof(float), stream);

    int nb2 = (n + 2 * TPB - 1) / (2 * TPB);

    k_mlp<<<nb2, TPB, 0, stream>>>(feats, coords, mask, W1, b1, W2, b2, W3, b3,
                                   out_off, slots, cursor, n);
    k_passA<<<NB / 4, TPB, 0, stream>>>(slots, cursor, ucnt);
    k_scanA<<<NCHUNK, 256, 0, stream>>>(ucnt, lstart, chsum);
    k_scanB<<<1, 1024, 0, stream>>>(chsum);
    k_passB<<<NB / 4, TPB, 0, stream>>>(slots, cursor, lstart, chsum, out_oc, out_inv);
}

// Round 2
// 557.209 us; speedup vs baseline: 6.8816x; 6.8816x over previous
//
#include <hip/hip_runtime.h>
#include <hip/hip_bf16.h>
#include <stdint.h>

// ---------------------------------------------------------------------------
// OffsetHead: pointwise MLP (64->32->16->3) + revoxelize (unique rows + means)
//
// R4 changes vs R2/R3:
//   * k_mlp: back to 1 row/thread (R3's 2-row version spilled: VGPR=256,
//     7.3 GB scratch traffic). Instead, rolling 8-deep float4 prefetch of the
//     feats row: 8 global loads in flight per thread (R2 had ~1-2), peak live
//     regs ~= 32 row + 32 acc -> no spill. Per-row fmaf order bitwise-
//     identical to R2 (only load scheduling changes).
//   * k_passA persists the sorted bucket; k_passB skips the bitonic re-sort
//     (verified win in R3: non-mlp time 424 -> 352 us).
// ---------------------------------------------------------------------------

#define TPB 256
#define NB 139264          // 2048 * 68
#define NCHUNK 544         // NB / 256
typedef unsigned long long ull;

__device__ __forceinline__ void epilogue(
    int i, float o0, float o1, float o2,
    const int* __restrict__ coords, const unsigned char* __restrict__ mask,
    float* __restrict__ out_off, ull* __restrict__ slots,
    unsigned int* __restrict__ cursor)
{
    float m = mask[i] ? 1.0f : 0.0f;
    o0 *= m; o1 *= m; o2 *= m;
    out_off[(size_t)3 * i + 0] = o0;
    out_off[(size_t)3 * i + 1] = o1;
    out_off[(size_t)3 * i + 2] = o2;

    // Key build: round-half-even (rintf == v_rndne, matches jnp.round)
    int4 c = ((const int4*)coords)[i];
    int r1 = (int)rintf(o0), r2 = (int)rintf(o1), r3 = (int)rintf(o2);
    int c1u = c.y + r1, c2u = c.z + r2, c3u = c.w + r3;
    int c1s = min(max(c1u + 1024, 0), 8191);
    int c2s = min(max(c2u + 1024, 0), 8191);
    int c3s = min(max(c3u + 1024, 0), 8191);
    int bin1 = min(max((c1u + 64) >> 5, 0), 67);
    int b = c.x * 68 + bin1;
    ull row39 = ((ull)c1s << 26) | ((ull)c2s << 13) | (ull)c3s;
    ull packed = (row39 << 20) | (ull)(unsigned int)i;
    unsigned int j = atomicAdd(&cursor[b], 1u);
    if (j < 64u) slots[(size_t)b * 64 + j] = packed;
}

__global__ __launch_bounds__(256) void k_mlp(
    const float* __restrict__ feats, const int* __restrict__ coords,
    const unsigned char* __restrict__ mask,
    const float* __restrict__ W1, const float* __restrict__ b1,
    const float* __restrict__ W2, const float* __restrict__ b2,
    const float* __restrict__ W3, const float* __restrict__ b3,
    float* __restrict__ out_off, ull* __restrict__ slots,
    unsigned int* __restrict__ cursor, int n)
{
    __shared__ float sW1[2048];
    __shared__ float sW2[512];
    __shared__ float sW3[48];
    __shared__ float sb1[32];
    __shared__ float sb2[16];
    __shared__ float sb3[3];
    for (int t = threadIdx.x; t < 2048; t += TPB) sW1[t] = W1[t];
    for (int t = threadIdx.x; t < 512;  t += TPB) sW2[t] = W2[t];
    if (threadIdx.x < 48) sW3[threadIdx.x] = W3[threadIdx.x];
    if (threadIdx.x < 32) sb1[threadIdx.x] = b1[threadIdx.x];
    if (threadIdx.x < 16) sb2[threadIdx.x] = b2[threadIdx.x];
    if (threadIdx.x < 3)  sb3[threadIdx.x] = b3[threadIdx.x];
    __syncthreads();

    int i = blockIdx.x * TPB + threadIdx.x;
    if (i >= n) return;

    const float4* f4 = (const float4*)(feats + (size_t)i * 64);

    // Rolling 8-deep prefetch: 8 loads in flight, 32 VGPRs of row state.
    float4 r[8];
    #pragma unroll
    for (int p = 0; p < 8; ++p) r[p] = f4[p];

    // Layer 1: ascending-k FMA accumulation, bias added AFTER (match XLA GEMM)
    float h1[32];
    #pragma unroll
    for (int j = 0; j < 32; ++j) h1[j] = 0.0f;
    #pragma unroll
    for (int kc = 0; kc < 16; ++kc) {
        float4 xv = r[kc & 7];
        if (kc < 8) r[kc & 7] = f4[kc + 8];   // refill after consume
        #pragma unroll
        for (int d = 0; d < 4; ++d) {
            float x = (d == 0) ? xv.x : (d == 1) ? xv.y : (d == 2) ? xv.z : xv.w;
            const float* wr = &sW1[(kc * 4 + d) * 32];
            #pragma unroll
            for (int j = 0; j < 32; j += 4) {
                float4 w = *(const float4*)(wr + j);
                h1[j + 0] = fmaf(x, w.x, h1[j + 0]);
                h1[j + 1] = fmaf(x, w.y, h1[j + 1]);
                h1[j + 2] = fmaf(x, w.z, h1[j + 2]);
                h1[j + 3] = fmaf(x, w.w, h1[j + 3]);
            }
        }
    }
    #pragma unroll
    for (int j = 0; j < 32; ++j) h1[j] = fmaxf(h1[j] + sb1[j], 0.0f);

    // Layer 2
    float h2[16];
    #pragma unroll
    for (int j = 0; j < 16; ++j) h2[j] = 0.0f;
    #pragma unroll
    for (int k = 0; k < 32; ++k) {
        float x = h1[k];
        const float* wr = &sW2[k * 16];
        #pragma unroll
        for (int j = 0; j < 16; j += 4) {
            float4 w = *(const float4*)(wr + j);
            h2[j + 0] = fmaf(x, w.x, h2[j + 0]);
            h2[j + 1] = fmaf(x, w.y, h2[j + 1]);
            h2[j + 2] = fmaf(x, w.z, h2[j + 2]);
            h2[j + 3] = fmaf(x, w.w, h2[j + 3]);
        }
    }
    #pragma unroll
    for (int j = 0; j < 16; ++j) h2[j] = fmaxf(h2[j] + sb2[j], 0.0f);

    // Layer 3
    float o0 = 0.0f, o1 = 0.0f, o2 = 0.0f;
    #pragma unroll
    for (int k = 0; k < 16; ++k) {
        float x = h2[k];
        o0 = fmaf(x, sW3[k * 3 + 0], o0);
        o1 = fmaf(x, sW3[k * 3 + 1], o1);
        o2 = fmaf(x, sW3[k * 3 + 2], o2);
    }
    o0 += sb3[0]; o1 += sb3[1]; o2 += sb3[2];

    epilogue(i, o0, o1, o2, coords, mask, out_off, slots, cursor);
}

// Wave-register bitonic sort of up to 64 packed u64s (padding = ~0ULL).
__device__ inline ull wave_sort64(ull v, int lane)
{
    #pragma unroll
    for (int k = 2; k <= 64; k <<= 1) {
        #pragma unroll
        for (int j = k >> 1; j > 0; j >>= 1) {
            ull o = __shfl_xor(v, j, 64);
            bool up = ((lane & k) == 0);
            bool lower = ((lane & j) == 0);
            ull mn = (v < o) ? v : o;
            ull mx = (v < o) ? o : v;
            v = (up == lower) ? mn : mx;
        }
    }
    return v;
}

// Pass A: sort each bucket, write sorted bucket back, count unique rows.
__global__ __launch_bounds__(256) void k_passA(
    ull* __restrict__ slots, const unsigned int* __restrict__ cursor,
    unsigned int* __restrict__ ucnt)
{
    int lane = threadIdx.x & 63;
    int b = blockIdx.x * 4 + (threadIdx.x >> 6);
    unsigned int cnt = cursor[b];
    if (cnt > 64u) cnt = 64u;
    if (cnt == 0u) { if (lane == 0) ucnt[b] = 0u; return; }
    ull v = (lane < (int)cnt) ? slots[(size_t)b * 64 + lane] : ~0ULL;
    v = wave_sort64(v, lane);
    if (lane < (int)cnt) slots[(size_t)b * 64 + lane] = v;  // persist sorted
    ull row = v >> 20;
    ull prev = __shfl_up(row, 1, 64);
    bool head = (lane < (int)cnt) && ((lane == 0) || (row != prev));
    ull hm = __ballot(head);
    if (lane == 0) ucnt[b] = (unsigned int)__popcll(hm);
}

// Scan level 1: exclusive scan within 256-entry chunks.
__global__ __launch_bounds__(256) void k_scanA(
    const unsigned int* __restrict__ ucnt, unsigned int* __restrict__ lstart,
    unsigned int* __restrict__ chsum)
{
    __shared__ unsigned int s[256];
    int tid = threadIdx.x;
    int g = blockIdx.x * 256 + tid;
    unsigned int v = ucnt[g];
    s[tid] = v;
    __syncthreads();
    for (int ofs = 1; ofs < 256; ofs <<= 1) {
        unsigned int t = (tid >= ofs) ? s[tid - ofs] : 0u;
        __syncthreads();
        s[tid] += t;
        __syncthreads();
    }
    lstart[g] = s[tid] - v;
    if (tid == 255) chsum[blockIdx.x] = s[255];
}

// Scan level 2: exclusive scan of chunk sums (in place).
__global__ __launch_bounds__(1024) void k_scanB(unsigned int* __restrict__ chsum)
{
    __shared__ unsigned int s[1024];
    int tid = threadIdx.x;
    unsigned int v = (tid < NCHUNK) ? chsum[tid] : 0u;
    s[tid] = v;
    __syncthreads();
    for (int ofs = 1; ofs < 1024; ofs <<= 1) {
        unsigned int t = (tid >= ofs) ? s[tid - ofs] : 0u;
        __syncthreads();
        s[tid] += t;
        __syncthreads();
    }
    if (tid < NCHUNK) chsum[tid] = s[tid] - v;
}

// Pass B: read pre-sorted buckets, compute global ranks, write inv + means.
__global__ __launch_bounds__(256) void k_passB(
    const ull* __restrict__ slots, const unsigned int* __restrict__ cursor,
    const unsigned int* __restrict__ lstart, const unsigned int* __restrict__ chbase,
    float* __restrict__ out_oc, float* __restrict__ out_inv)
{
    int lane = threadIdx.x & 63;
    int b = blockIdx.x * 4 + (threadIdx.x >> 6);
    unsigned int cnt = cursor[b];
    if (cnt > 64u) cnt = 64u;
    if (cnt == 0u) return;
    // slots[b] was sorted in-place by k_passA; no re-sort needed.
    ull v = (lane < (int)cnt) ? slots[(size_t)b * 64 + lane] : ~0ULL;
    ull row = v >> 20;
    unsigned int idx = (unsigned int)(v & 0xFFFFFULL);
    ull prev = __shfl_up(row, 1, 64);
    bool head = (lane < (int)cnt) && ((lane == 0) || (row != prev));
    ull hm = __ballot(head);
    ull le = (lane == 63) ? ~0ULL : ((1ULL << (lane + 1)) - 1ULL);
    int lrank = __popcll(hm & le) - 1;          // 0-based within bucket
    unsigned int base = chbase[b >> 8] + lstart[b];
    unsigned int r = base + (unsigned int)lrank;
    if (lane < (int)cnt) out_inv[idx] = (float)r;

    // packed (count, c1sum, c2sum, c3sum): 7 + 19 + 19 + 19 bits
    int c3s = (int)(row & 0x1FFFULL);
    int c2s = (int)((row >> 13) & 0x1FFFULL);
    int c1s = (int)(row >> 26);
    ull sum = (lane < (int)cnt)
        ? ((1ULL << 57) | ((ull)c1s << 38) | ((ull)c2s << 19) | (ull)c3s)
        : 0ULL;
    ull P = sum;
    #pragma unroll
    for (int d = 1; d < 64; d <<= 1) {
        ull t = __shfl_up(P, d, 64);
        if (lane >= d) P += t;
    }
    ull gt = hm & ~le;                          // heads strictly above this lane
    int tpos = gt ? (__ffsll((long long)gt) - 2) : ((int)cnt - 1);
    ull Pt = __shfl(P, tpos, 64);
    int hsrc = (lane > 0) ? lane - 1 : 0;
    ull Ph = __shfl(P, hsrc, 64);
    if (lane == 0) Ph = 0ULL;
    if (head) {
        ull run = Pt - Ph;
        int rc = (int)(run >> 57);
        int s1 = (int)((run >> 38) & 0x7FFFFULL) - 1024 * rc;
        int s2 = (int)((run >> 19) & 0x7FFFFULL) - 1024 * rc;
        int s3 = (int)(run & 0x7FFFFULL) - 1024 * rc;
        float fc = (float)rc;
        float4 o;
        o.x = (float)((unsigned int)b / 68u);   // dim0 unchanged -> exact mean
        o.y = truncf((float)s1 / fc);
        o.z = truncf((float)s2 / fc);
        o.w = truncf((float)s3 / fc);
        ((float4*)out_oc)[r] = o;
    }
}

extern "C" void kernel_launch(void* const* d_in, const int* in_sizes, int n_in,
                              void* d_out, int out_size, void* d_ws, size_t ws_size,
                              hipStream_t stream)
{
    const float*         feats  = (const float*)d_in[0];
    const int*           coords = (const int*)d_in[1];
    const unsigned char* mask   = (const unsigned char*)d_in[2];
    const float* W1 = (const float*)d_in[3];
    const float* b1 = (const float*)d_in[4];
    const float* W2 = (const float*)d_in[5];
    const float* b2 = (const float*)d_in[6];
    const float* W3 = (const float*)d_in[7];
    const float* b3 = (const float*)d_in[8];

    int n = in_sizes[1] / 4;  // coords is [N,4]

    char* ws = (char*)d_ws;
    ull*          slots  = (ull*)ws;                                   // NB*64*8
    unsigned int* cursor = (unsigned int*)(ws + (size_t)NB * 64 * 8);  // NB*4 (zeroed)
    unsigned int* ucnt   = cursor + NB;                                // NB*4
    unsigned int* lstart = ucnt + NB;                                  // NB*4
    unsigned int* chsum  = lstart + NB;                                // NCHUNK*4

    float* out     = (float*)d_out;
    float* out_off = out;                  // [N,3] offsets (float32)
    float* out_oc  = out + (size_t)3 * n;  // [N,4] out_coords (as float values)
    float* out_inv = out + (size_t)7 * n;  // [N]   inv (as float values)

    hipMemsetAsync(cursor, 0, (size_t)NB * sizeof(unsigned int), stream);
    hipMemsetAsync(out_oc, 0, (size_t)4 * n * sizeof(float), stream);

    int nb256 = (n + TPB - 1) / TPB;

    k_mlp<<<nb256, TPB, 0, stream>>>(feats, coords, mask, W1, b1, W2, b2, W3, b3,
                                     out_off, slots, cursor, n);
    k_passA<<<NB / 4, TPB, 0, stream>>>(slots, cursor, ucnt);
    k_scanA<<<NCHUNK, 256, 0, stream>>>(ucnt, lstart, chsum);
    k_scanB<<<1, 1024, 0, stream>>>(chsum);
    k_passB<<<NB / 4, TPB, 0, stream>>>(slots, cursor, lstart, chsum, out_oc, out_inv);
}

// Round 4
// 543.028 us; speedup vs baseline: 7.0613x; 1.0261x over previous
//
#include <hip/hip_runtime.h>
#include <hip/hip_bf16.h>
#include <stdint.h>

// ---------------------------------------------------------------------------
// OffsetHead: pointwise MLP (64->32->16->3) + revoxelize (unique rows + means)
//
// R6 == R5 resubmit (R5 bench was an infra failure: container acquire died,
// no kernel signal). One hardening fix: k_fixinv clamps the decoded bucket
// id so a (P~1e-30) bucket overflow cannot cause an OOB workspace read.
//
// R5 changes vs R4:
//   * k_mlp: no LDS. Weight/bias addresses are wave-uniform (kernel-arg base
//     + compile-time offsets) -> compiler emits s_load into SGPRs, FMAs read
//     the weight as the one-SGPR operand. Removes ~650 ds_read issues/thread,
//     the staging loop and __syncthreads. FMA chain order per accumulator is
//     unchanged (operand source only) -> bitwise-identical results.
//   * k_passA: cnt-adaptive bitonic (width 8/16/32/64; lambda~7.6 so most
//     buckets sort in 6 steps, not 21). passA now also does the packed-sum
//     prefix scan: writes per-element (b*64+lrank) as u32 bits into out_inv,
//     and compacted per-unique run-sums back into slots[b*64+lrank].
//   * k_passB deleted. Replaced by k_fixinv (N threads, inv = base+lrank) and
//     k_fixout (wave/bucket, lane u<ucnt: coalesced run load, means, coalesced
//     float4 store; no shuffles, no sort).
// ---------------------------------------------------------------------------

#define TPB 256
#define NB 139264          // 2048 * 68
#define NCHUNK 544         // NB / 256
typedef unsigned long long ull;

// --------------------------------------------------------------------------
// MLP + bucket insert
// --------------------------------------------------------------------------
__global__ __launch_bounds__(256) void k_mlp(
    const float* __restrict__ feats, const int* __restrict__ coords,
    const unsigned char* __restrict__ mask,
    const float* __restrict__ W1, const float* __restrict__ b1,
    const float* __restrict__ W2, const float* __restrict__ b2,
    const float* __restrict__ W3, const float* __restrict__ b3,
    float* __restrict__ out_off, ull* __restrict__ slots,
    unsigned int* __restrict__ cursor, int n)
{
    int i = blockIdx.x * TPB + threadIdx.x;
    if (i >= n) return;

    const float4* f4 = (const float4*)(feats + (size_t)i * 64);

    // Layer 1: ascending-k FMA accumulation, bias added AFTER (match XLA GEMM).
    // Weights read via uniform (scalar) loads - no LDS.
    float h1[32];
    #pragma unroll
    for (int j = 0; j < 32; ++j) h1[j] = 0.0f;
    #pragma unroll
    for (int kc = 0; kc < 16; ++kc) {
        float4 xv = f4[kc];
        #pragma unroll
        for (int d = 0; d < 4; ++d) {
            float x = (d == 0) ? xv.x : (d == 1) ? xv.y : (d == 2) ? xv.z : xv.w;
            const float* wr = W1 + (kc * 4 + d) * 32;
            #pragma unroll
            for (int j = 0; j < 32; j += 4) {
                float4 w = *(const float4*)(wr + j);
                h1[j + 0] = fmaf(x, w.x, h1[j + 0]);
                h1[j + 1] = fmaf(x, w.y, h1[j + 1]);
                h1[j + 2] = fmaf(x, w.z, h1[j + 2]);
                h1[j + 3] = fmaf(x, w.w, h1[j + 3]);
            }
        }
    }
    #pragma unroll
    for (int j = 0; j < 32; ++j) h1[j] = fmaxf(h1[j] + b1[j], 0.0f);

    // Layer 2
    float h2[16];
    #pragma unroll
    for (int j = 0; j < 16; ++j) h2[j] = 0.0f;
    #pragma unroll
    for (int k = 0; k < 32; ++k) {
        float x = h1[k];
        const float* wr = W2 + k * 16;
        #pragma unroll
        for (int j = 0; j < 16; j += 4) {
            float4 w = *(const float4*)(wr + j);
            h2[j + 0] = fmaf(x, w.x, h2[j + 0]);
            h2[j + 1] = fmaf(x, w.y, h2[j + 1]);
            h2[j + 2] = fmaf(x, w.z, h2[j + 2]);
            h2[j + 3] = fmaf(x, w.w, h2[j + 3]);
        }
    }
    #pragma unroll
    for (int j = 0; j < 16; ++j) h2[j] = fmaxf(h2[j] + b2[j], 0.0f);

    // Layer 3
    float o0 = 0.0f, o1 = 0.0f, o2 = 0.0f;
    #pragma unroll
    for (int k = 0; k < 16; ++k) {
        float x = h2[k];
        o0 = fmaf(x, W3[k * 3 + 0], o0);
        o1 = fmaf(x, W3[k * 3 + 1], o1);
        o2 = fmaf(x, W3[k * 3 + 2], o2);
    }
    o0 += b3[0]; o1 += b3[1]; o2 += b3[2];

    float m = mask[i] ? 1.0f : 0.0f;
    o0 *= m; o1 *= m; o2 *= m;
    out_off[(size_t)3 * i + 0] = o0;
    out_off[(size_t)3 * i + 1] = o1;
    out_off[(size_t)3 * i + 2] = o2;

    // Key build: round-half-even (rintf == v_rndne, matches jnp.round)
    int4 c = ((const int4*)coords)[i];
    int r1 = (int)rintf(o0), r2 = (int)rintf(o1), r3 = (int)rintf(o2);
    int c1u = c.y + r1, c2u = c.z + r2, c3u = c.w + r3;
    int c1s = min(max(c1u + 1024, 0), 8191);
    int c2s = min(max(c2u + 1024, 0), 8191);
    int c3s = min(max(c3u + 1024, 0), 8191);
    int bin1 = min(max((c1u + 64) >> 5, 0), 67);
    int b = c.x * 68 + bin1;
    ull row39 = ((ull)c1s << 26) | ((ull)c2s << 13) | (ull)c3s;
    ull packed = (row39 << 20) | (ull)(unsigned int)i;
    unsigned int j = atomicAdd(&cursor[b], 1u);
    if (j < 64u) slots[(size_t)b * 64 + j] = packed;
}

// --------------------------------------------------------------------------
// Segment-local bitonic sort of W elements (W-aligned lane groups).
// For k == W the (k & (W-1)) term is 0 -> final merge ascending in all
// segments; identical to the full-wave W=64 version when W=64.
// --------------------------------------------------------------------------
template<int W>
__device__ inline ull seg_sort(ull v, int lane)
{
    #pragma unroll
    for (int k = 2; k <= W; k <<= 1) {
        #pragma unroll
        for (int j = k >> 1; j > 0; j >>= 1) {
            ull o = __shfl_xor(v, j, 64);
            bool up = ((lane & (k & (W - 1))) == 0);
            bool lower = ((lane & j) == 0);
            ull mn = (v < o) ? v : o;
            ull mx = (v < o) ? o : v;
            v = (up == lower) ? mn : mx;
        }
    }
    return v;
}

// --------------------------------------------------------------------------
// Pass A: adaptive sort, heads, local ranks, packed run sums.
//   out_inv[idx]    <- u32 bits (b*64 + lrank)   (fixed up by k_fixinv)
//   slots[b*64+u]   <- packed run sum for unique u (consumed by k_fixout)
//   ucnt[b]         <- number of uniques
// --------------------------------------------------------------------------
__global__ __launch_bounds__(256) void k_passA(
    ull* __restrict__ slots, const unsigned int* __restrict__ cursor,
    unsigned int* __restrict__ ucnt, float* __restrict__ out_inv)
{
    int lane = threadIdx.x & 63;
    int b = blockIdx.x * 4 + (threadIdx.x >> 6);
    unsigned int cnt = cursor[b];
    if (cnt > 64u) cnt = 64u;
    if (cnt == 0u) { if (lane == 0) ucnt[b] = 0u; return; }
    ull v = (lane < (int)cnt) ? slots[(size_t)b * 64 + lane] : ~0ULL;
    if      (cnt <= 8u)  v = seg_sort<8>(v, lane);
    else if (cnt <= 16u) v = seg_sort<16>(v, lane);
    else if (cnt <= 32u) v = seg_sort<32>(v, lane);
    else                 v = seg_sort<64>(v, lane);

    ull row = v >> 20;
    unsigned int idx = (unsigned int)(v & 0xFFFFFULL);
    ull prev = __shfl_up(row, 1, 64);
    bool head = (lane < (int)cnt) && ((lane == 0) || (row != prev));
    ull hm = __ballot(head);
    ull le = (lane == 63) ? ~0ULL : ((1ULL << (lane + 1)) - 1ULL);
    int lrank = __popcll(hm & le) - 1;          // 0-based rank within bucket
    if (lane == 0) ucnt[b] = (unsigned int)__popcll(hm);
    if (lane < (int)cnt)
        ((unsigned int*)out_inv)[idx] = (unsigned int)(b * 64 + lrank);

    // packed (count, c1sum, c2sum, c3sum): 7 + 19 + 19 + 19 bits
    int c3s = (int)(row & 0x1FFFULL);
    int c2s = (int)((row >> 13) & 0x1FFFULL);
    int c1s = (int)(row >> 26);
    ull sum = (lane < (int)cnt)
        ? ((1ULL << 57) | ((ull)c1s << 38) | ((ull)c2s << 19) | (ull)c3s)
        : 0ULL;
    ull P = sum;
    #pragma unroll
    for (int d = 1; d < 64; d <<= 1) {
        ull t = __shfl_up(P, d, 64);
        if (lane >= d) P += t;
    }
    ull gt = hm & ~le;                          // heads strictly above this lane
    int tpos = gt ? (__ffsll((long long)gt) - 2) : ((int)cnt - 1);
    ull Pt = __shfl(P, tpos, 64);
    int hsrc = (lane > 0) ? lane - 1 : 0;
    ull Ph = __shfl(P, hsrc, 64);
    if (lane == 0) Ph = 0ULL;
    if (head) slots[(size_t)b * 64 + lrank] = Pt - Ph;  // compacted run sums
}

// Scan level 1: exclusive scan within 256-entry chunks.
__global__ __launch_bounds__(256) void k_scanA(
    const unsigned int* __restrict__ ucnt, unsigned int* __restrict__ lstart,
    unsigned int* __restrict__ chsum)
{
    __shared__ unsigned int s[256];
    int tid = threadIdx.x;
    int g = blockIdx.x * 256 + tid;
    unsigned int v = ucnt[g];
    s[tid] = v;
    __syncthreads();
    for (int ofs = 1; ofs < 256; ofs <<= 1) {
        unsigned int t = (tid >= ofs) ? s[tid - ofs] : 0u;
        __syncthreads();
        s[tid] += t;
        __syncthreads();
    }
    lstart[g] = s[tid] - v;
    if (tid == 255) chsum[blockIdx.x] = s[255];
}

// Scan level 2: exclusive scan of chunk sums (in place).
__global__ __launch_bounds__(1024) void k_scanB(unsigned int* __restrict__ chsum)
{
    __shared__ unsigned int s[1024];
    int tid = threadIdx.x;
    unsigned int v = (tid < NCHUNK) ? chsum[tid] : 0u;
    s[tid] = v;
    __syncthreads();
    for (int ofs = 1; ofs < 1024; ofs <<= 1) {
        unsigned int t = (tid >= ofs) ? s[tid - ofs] : 0u;
        __syncthreads();
        s[tid] += t;
        __syncthreads();
    }
    if (tid < NCHUNK) chsum[tid] = s[tid] - v;
}

// Fix-up inv: out_inv currently holds u32 (b*64 + lrank); add global base.
__global__ __launch_bounds__(256) void k_fixinv(
    float* __restrict__ out_inv, const unsigned int* __restrict__ lstart,
    const unsigned int* __restrict__ chbase, int n)
{
    int i = blockIdx.x * TPB + threadIdx.x;
    if (i >= n) return;
    unsigned int q = ((const unsigned int*)out_inv)[i];
    unsigned int b = q >> 6, lr = q & 63u;
    if (b >= NB) b = NB - 1;                    // overflow hardening (no OOB)
    out_inv[i] = (float)(chbase[b >> 8] + lstart[b] + lr);
}

// Write per-cluster means: lane u < ucnt[b] owns unique u of bucket b.
__global__ __launch_bounds__(256) void k_fixout(
    const ull* __restrict__ slots, const unsigned int* __restrict__ ucnt,
    const unsigned int* __restrict__ lstart, const unsigned int* __restrict__ chbase,
    float* __restrict__ out_oc)
{
    int lane = threadIdx.x & 63;
    int b = blockIdx.x * 4 + (threadIdx.x >> 6);
    unsigned int uc = ucnt[b];
    if (lane >= (int)uc) return;
    ull run = slots[(size_t)b * 64 + lane];
    unsigned int r = chbase[b >> 8] + lstart[b] + (unsigned int)lane;
    int rc = (int)(run >> 57);
    int s1 = (int)((run >> 38) & 0x7FFFFULL) - 1024 * rc;
    int s2 = (int)((run >> 19) & 0x7FFFFULL) - 1024 * rc;
    int s3 = (int)(run & 0x7FFFFULL) - 1024 * rc;
    float fc = (float)rc;
    float4 o;
    o.x = (float)((unsigned int)b / 68u);       // dim0 unchanged -> exact mean
    o.y = truncf((float)s1 / fc);
    o.z = truncf((float)s2 / fc);
    o.w = truncf((float)s3 / fc);
    ((float4*)out_oc)[r] = o;
}

extern "C" void kernel_launch(void* const* d_in, const int* in_sizes, int n_in,
                              void* d_out, int out_size, void* d_ws, size_t ws_size,
                              hipStream_t stream)
{
    const float*         feats  = (const float*)d_in[0];
    const int*           coords = (const int*)d_in[1];
    const unsigned char* mask   = (const unsigned char*)d_in[2];
    const float* W1 = (const float*)d_in[3];
    const float* b1 = (const float*)d_in[4];
    const float* W2 = (const float*)d_in[5];
    const float* b2 = (const float*)d_in[6];
    const float* W3 = (const float*)d_in[7];
    const float* b3 = (const float*)d_in[8];

    int n = in_sizes[1] / 4;  // coords is [N,4]

    char* ws = (char*)d_ws;
    ull*          slots  = (ull*)ws;                                   // NB*64*8
    unsigned int* cursor = (unsigned int*)(ws + (size_t)NB * 64 * 8);  // NB*4 (zeroed)
    unsigned int* ucnt   = cursor + NB;                                // NB*4
    unsigned int* lstart = ucnt + NB;                                  // NB*4
    unsigned int* chsum  = lstart + NB;                                // NCHUNK*4

    float* out     = (float*)d_out;
    float* out_off = out;                  // [N,3] offsets (float32)
    float* out_oc  = out + (size_t)3 * n;  // [N,4] out_coords (as float values)
    float* out_inv = out + (size_t)7 * n;  // [N]   inv (as float values)

    hipMemsetAsync(cursor, 0, (size_t)NB * sizeof(unsigned int), stream);
    hipMemsetAsync(out_oc, 0, (size_t)4 * n * sizeof(float), stream);

    int nb256 = (n + TPB - 1) / TPB;

    k_mlp<<<nb256, TPB, 0, stream>>>(feats, coords, mask, W1, b1, W2, b2, W3, b3,
                                     out_off, slots, cursor, n);
    k_passA<<<NB / 4, TPB, 0, stream>>>(slots, cursor, ucnt, out_inv);
    k_scanA<<<NCHUNK, 256, 0, stream>>>(ucnt, lstart, chsum);
    k_scanB<<<1, 1024, 0, stream>>>(chsum);
    k_fixinv<<<nb256, TPB, 0, stream>>>(out_inv, lstart, chsum, n);
    k_fixout<<<NB / 4, TPB, 0, stream>>>(slots, ucnt, lstart, chsum, out_oc);
}

// Round 5
// 530.477 us; speedup vs baseline: 7.2284x; 1.0237x over previous
//
#include <hip/hip_runtime.h>
#include <hip/hip_bf16.h>
#include <stdint.h>

// ---------------------------------------------------------------------------
// OffsetHead: pointwise MLP (64->32->16->3) + revoxelize (unique rows + means)
//
// R7 changes vs R6:
//   * k_mlp: all 16 feats float4 loads issued up-front and pinned live via a
//     single inline-asm "+v" barrier (compiler was sinking them: VGPR=36,
//     ~2 loads in flight, 16 latency stalls/row). Now: one stall per row.
//     FMA order unchanged -> bitwise-identical offsets.
//   * k_passA: whole body templated on W (8/16/32/64) - sort AND u64 prefix
//     scan now both adaptive (cnt<=8 -> 3 scan steps, not 6).
//   * k_fixout (139k waves) deleted. k_final (per-element, 15.6k waves) does
//     inv fixup AND the mean write: every member of a run writes the same
//     float4 to out_oc[r] (idempotent). r<n guard for overflow hardening.
// ---------------------------------------------------------------------------

#define TPB 256
#define NB 139264          // 2048 * 68
#define NCHUNK 544         // NB / 256
typedef unsigned long long ull;
typedef float vf4 __attribute__((ext_vector_type(4)));

// --------------------------------------------------------------------------
// MLP + bucket insert
// --------------------------------------------------------------------------
__global__ __launch_bounds__(256) void k_mlp(
    const float* __restrict__ feats, const int* __restrict__ coords,
    const unsigned char* __restrict__ mask,
    const float* __restrict__ W1, const float* __restrict__ b1,
    const float* __restrict__ W2, const float* __restrict__ b2,
    const float* __restrict__ W3, const float* __restrict__ b3,
    float* __restrict__ out_off, ull* __restrict__ slots,
    unsigned int* __restrict__ cursor, int n)
{
    int i = blockIdx.x * TPB + threadIdx.x;
    if (i >= n) return;

    const vf4* f4 = (const vf4*)(feats + (size_t)i * 64);

    // Issue ALL 16 row loads, then pin them live with one asm barrier:
    // every load must complete before the asm (inputs), every FMA must
    // follow it (outputs) -> compiler cannot re-sink the loads.
    vf4 r[16];
    #pragma unroll
    for (int p = 0; p < 16; ++p) r[p] = f4[p];
    asm volatile("" : "+v"(r[0]), "+v"(r[1]), "+v"(r[2]), "+v"(r[3]),
                      "+v"(r[4]), "+v"(r[5]), "+v"(r[6]), "+v"(r[7]),
                      "+v"(r[8]), "+v"(r[9]), "+v"(r[10]), "+v"(r[11]),
                      "+v"(r[12]), "+v"(r[13]), "+v"(r[14]), "+v"(r[15]));

    // Layer 1: ascending-k FMA accumulation, bias added AFTER (match XLA GEMM).
    // Weights via uniform (scalar) loads - no LDS.
    float h1[32];
    #pragma unroll
    for (int j = 0; j < 32; ++j) h1[j] = 0.0f;
    #pragma unroll
    for (int kc = 0; kc < 16; ++kc) {
        vf4 xv = r[kc];
        #pragma unroll
        for (int d = 0; d < 4; ++d) {
            float x = (d == 0) ? xv.x : (d == 1) ? xv.y : (d == 2) ? xv.z : xv.w;
            const float* wr = W1 + (kc * 4 + d) * 32;
            #pragma unroll
            for (int j = 0; j < 32; j += 4) {
                float4 w = *(const float4*)(wr + j);
                h1[j + 0] = fmaf(x, w.x, h1[j + 0]);
                h1[j + 1] = fmaf(x, w.y, h1[j + 1]);
                h1[j + 2] = fmaf(x, w.z, h1[j + 2]);
                h1[j + 3] = fmaf(x, w.w, h1[j + 3]);
            }
        }
    }
    #pragma unroll
    for (int j = 0; j < 32; ++j) h1[j] = fmaxf(h1[j] + b1[j], 0.0f);

    // Layer 2
    float h2[16];
    #pragma unroll
    for (int j = 0; j < 16; ++j) h2[j] = 0.0f;
    #pragma unroll
    for (int k = 0; k < 32; ++k) {
        float x = h1[k];
        const float* wr = W2 + k * 16;
        #pragma unroll
        for (int j = 0; j < 16; j += 4) {
            float4 w = *(const float4*)(wr + j);
            h2[j + 0] = fmaf(x, w.x, h2[j + 0]);
            h2[j + 1] = fmaf(x, w.y, h2[j + 1]);
            h2[j + 2] = fmaf(x, w.z, h2[j + 2]);
            h2[j + 3] = fmaf(x, w.w, h2[j + 3]);
        }
    }
    #pragma unroll
    for (int j = 0; j < 16; ++j) h2[j] = fmaxf(h2[j] + b2[j], 0.0f);

    // Layer 3
    float o0 = 0.0f, o1 = 0.0f, o2 = 0.0f;
    #pragma unroll
    for (int k = 0; k < 16; ++k) {
        float x = h2[k];
        o0 = fmaf(x, W3[k * 3 + 0], o0);
        o1 = fmaf(x, W3[k * 3 + 1], o1);
        o2 = fmaf(x, W3[k * 3 + 2], o2);
    }
    o0 += b3[0]; o1 += b3[1]; o2 += b3[2];

    float m = mask[i] ? 1.0f : 0.0f;
    o0 *= m; o1 *= m; o2 *= m;
    out_off[(size_t)3 * i + 0] = o0;
    out_off[(size_t)3 * i + 1] = o1;
    out_off[(size_t)3 * i + 2] = o2;

    // Key build: round-half-even (rintf == v_rndne, matches jnp.round)
    int4 c = ((const int4*)coords)[i];
    int r1 = (int)rintf(o0), r2 = (int)rintf(o1), r3 = (int)rintf(o2);
    int c1u = c.y + r1, c2u = c.z + r2, c3u = c.w + r3;
    int c1s = min(max(c1u + 1024, 0), 8191);
    int c2s = min(max(c2u + 1024, 0), 8191);
    int c3s = min(max(c3u + 1024, 0), 8191);
    int bin1 = min(max((c1u + 64) >> 5, 0), 67);
    int b = c.x * 68 + bin1;
    ull row39 = ((ull)c1s << 26) | ((ull)c2s << 13) | (ull)c3s;
    ull packed = (row39 << 20) | (ull)(unsigned int)i;
    unsigned int j = atomicAdd(&cursor[b], 1u);
    if (j < 64u) slots[(size_t)b * 64 + j] = packed;
}

// --------------------------------------------------------------------------
// Segment-local bitonic sort of W elements (W-aligned lane groups).
// For k == W the (k & (W-1)) term is 0 -> final merge ascending.
// --------------------------------------------------------------------------
template<int W>
__device__ inline ull seg_sort(ull v, int lane)
{
    #pragma unroll
    for (int k = 2; k <= W; k <<= 1) {
        #pragma unroll
        for (int j = k >> 1; j > 0; j >>= 1) {
            ull o = __shfl_xor(v, j, 64);
            bool up = ((lane & (k & (W - 1))) == 0);
            bool lower = ((lane & j) == 0);
            ull mn = (v < o) ? v : o;
            ull mx = (v < o) ? o : v;
            v = (up == lower) ? mn : mx;
        }
    }
    return v;
}

// --------------------------------------------------------------------------
// Pass A body, templated on bucket width W (cnt <= W <= 64).
// All data lives in lanes 0..cnt-1 (< W), so sort AND scan are W-wide.
// --------------------------------------------------------------------------
template<int W>
__device__ inline void passA_body(
    ull* __restrict__ slots, unsigned int* __restrict__ ucnt,
    unsigned int* __restrict__ inv_bits, int b, int lane, unsigned int cnt)
{
    ull v = (lane < (int)cnt) ? slots[(size_t)b * 64 + lane] : ~0ULL;
    v = seg_sort<W>(v, lane);

    ull row = v >> 20;
    unsigned int idx = (unsigned int)(v & 0xFFFFFULL);
    ull prev = __shfl_up(row, 1, 64);
    bool head = (lane < (int)cnt) && ((lane == 0) || (row != prev));
    ull hm = __ballot(head);
    ull le = (lane == 63) ? ~0ULL : ((1ULL << (lane + 1)) - 1ULL);
    int lrank = __popcll(hm & le) - 1;          // 0-based rank within bucket
    if (lane == 0) ucnt[b] = (unsigned int)__popcll(hm);
    if (lane < (int)cnt)
        inv_bits[idx] = (unsigned int)(b * 64 + lrank);

    // packed (count, c1sum, c2sum, c3sum): 7 + 19 + 19 + 19 bits
    int c3s = (int)(row & 0x1FFFULL);
    int c2s = (int)((row >> 13) & 0x1FFFULL);
    int c1s = (int)(row >> 26);
    ull sum = (lane < (int)cnt)
        ? ((1ULL << 57) | ((ull)c1s << 38) | ((ull)c2s << 19) | (ull)c3s)
        : 0ULL;
    ull P = sum;
    #pragma unroll
    for (int d = 1; d < W; d <<= 1) {
        ull t = __shfl_up(P, d, 64);
        if (lane >= d) P += t;
    }
    ull gt = hm & ~le;                          // heads strictly above this lane
    int tpos = gt ? (__ffsll((long long)gt) - 2) : ((int)cnt - 1);
    ull Pt = __shfl(P, tpos, 64);
    int hsrc = (lane > 0) ? lane - 1 : 0;
    ull Ph = __shfl(P, hsrc, 64);
    if (lane == 0) Ph = 0ULL;
    if (head) slots[(size_t)b * 64 + lrank] = Pt - Ph;  // compacted run sums
}

__global__ __launch_bounds__(256) void k_passA(
    ull* __restrict__ slots, const unsigned int* __restrict__ cursor,
    unsigned int* __restrict__ ucnt, float* __restrict__ out_inv)
{
    int lane = threadIdx.x & 63;
    int b = blockIdx.x * 4 + (threadIdx.x >> 6);
    unsigned int cnt = cursor[b];
    if (cnt > 64u) cnt = 64u;
    if (cnt == 0u) { if (lane == 0) ucnt[b] = 0u; return; }
    unsigned int* inv_bits = (unsigned int*)out_inv;
    if      (cnt <= 8u)  passA_body<8> (slots, ucnt, inv_bits, b, lane, cnt);
    else if (cnt <= 16u) passA_body<16>(slots, ucnt, inv_bits, b, lane, cnt);
    else if (cnt <= 32u) passA_body<32>(slots, ucnt, inv_bits, b, lane, cnt);
    else                 passA_body<64>(slots, ucnt, inv_bits, b, lane, cnt);
}

// Scan level 1: exclusive scan within 256-entry chunks.
__global__ __launch_bounds__(256) void k_scanA(
    const unsigned int* __restrict__ ucnt, unsigned int* __restrict__ lstart,
    unsigned int* __restrict__ chsum)
{
    __shared__ unsigned int s[256];
    int tid = threadIdx.x;
    int g = blockIdx.x * 256 + tid;
    unsigned int v = ucnt[g];
    s[tid] = v;
    __syncthreads();
    for (int ofs = 1; ofs < 256; ofs <<= 1) {
        unsigned int t = (tid >= ofs) ? s[tid - ofs] : 0u;
        __syncthreads();
        s[tid] += t;
        __syncthreads();
    }
    lstart[g] = s[tid] - v;
    if (tid == 255) chsum[blockIdx.x] = s[255];
}

// Scan level 2: exclusive scan of chunk sums (in place).
__global__ __launch_bounds__(1024) void k_scanB(unsigned int* __restrict__ chsum)
{
    __shared__ unsigned int s[1024];
    int tid = threadIdx.x;
    unsigned int v = (tid < NCHUNK) ? chsum[tid] : 0u;
    s[tid] = v;
    __syncthreads();
    for (int ofs = 1; ofs < 1024; ofs <<= 1) {
        unsigned int t = (tid >= ofs) ? s[tid - ofs] : 0u;
        __syncthreads();
        s[tid] += t;
        __syncthreads();
    }
    if (tid < NCHUNK) chsum[tid] = s[tid] - v;
}

// Final: per element, resolve global rank AND write the cluster mean.
// All members of a run write the identical float4 -> idempotent, race-free.
__global__ __launch_bounds__(256) void k_final(
    float* __restrict__ out_inv, float* __restrict__ out_oc,
    const ull* __restrict__ slots, const unsigned int* __restrict__ lstart,
    const unsigned int* __restrict__ chbase, int n)
{
    int i = blockIdx.x * TPB + threadIdx.x;
    if (i >= n) return;
    unsigned int q = ((const unsigned int*)out_inv)[i];
    unsigned int b = q >> 6, lr = q & 63u;
    if (b >= NB) b = NB - 1;                    // overflow hardening (no OOB)
    unsigned int r = chbase[b >> 8] + lstart[b] + lr;
    out_inv[i] = (float)r;
    if (r < (unsigned int)n) {
        ull run = slots[(size_t)b * 64 + lr];
        int rc = (int)(run >> 57);
        int s1 = (int)((run >> 38) & 0x7FFFFULL) - 1024 * rc;
        int s2 = (int)((run >> 19) & 0x7FFFFULL) - 1024 * rc;
        int s3 = (int)(run & 0x7FFFFULL) - 1024 * rc;
        float fc = (float)rc;
        float4 o;
        o.x = (float)(b / 68u);                 // dim0 unchanged -> exact mean
        o.y = truncf((float)s1 / fc);
        o.z = truncf((float)s2 / fc);
        o.w = truncf((float)s3 / fc);
        ((float4*)out_oc)[r] = o;
    }
}

extern "C" void kernel_launch(void* const* d_in, const int* in_sizes, int n_in,
                              void* d_out, int out_size, void* d_ws, size_t ws_size,
                              hipStream_t stream)
{
    const float*         feats  = (const float*)d_in[0];
    const int*           coords = (const int*)d_in[1];
    const unsigned char* mask   = (const unsigned char*)d_in[2];
    const float* W1 = (const float*)d_in[3];
    const float* b1 = (const float*)d_in[4];
    const float* W2 = (const float*)d_in[5];
    const float* b2 = (const float*)d_in[6];
    const float* W3 = (const float*)d_in[7];
    const float* b3 = (const float*)d_in[8];

    int n = in_sizes[1] / 4;  // coords is [N,4]

    char* ws = (char*)d_ws;
    ull*          slots  = (ull*)ws;                                   // NB*64*8
    unsigned int* cursor = (unsigned int*)(ws + (size_t)NB * 64 * 8);  // NB*4 (zeroed)
    unsigned int* ucnt   = cursor + NB;                                // NB*4
    unsigned int* lstart = ucnt + NB;                                  // NB*4
    unsigned int* chsum  = lstart + NB;                                // NCHUNK*4

    float* out     = (float*)d_out;
    float* out_off = out;                  // [N,3] offsets (float32)
    float* out_oc  = out + (size_t)3 * n;  // [N,4] out_coords (as float values)
    float* out_inv = out + (size_t)7 * n;  // [N]   inv (as float values)

    hipMemsetAsync(cursor, 0, (size_t)NB * sizeof(unsigned int), stream);
    hipMemsetAsync(out_oc, 0, (size_t)4 * n * sizeof(float), stream);

    int nb256 = (n + TPB - 1) / TPB;

    k_mlp<<<nb256, TPB, 0, stream>>>(feats, coords, mask, W1, b1, W2, b2, W3, b3,
                                     out_off, slots, cursor, n);
    k_passA<<<NB / 4, TPB, 0, stream>>>(slots, cursor, ucnt, out_inv);
    k_scanA<<<NCHUNK, 256, 0, stream>>>(ucnt, lstart, chsum);
    k_scanB<<<1, 1024, 0, stream>>>(chsum);
    k_final<<<nb256, TPB, 0, stream>>>(out_inv, out_oc, slots, lstart, chsum, n);
}